// Round 3
// baseline (902.078 us; speedup 1.0000x reference)
//
#include <hip/hip_runtime.h>
#include <math.h>

#define NN 100000
#define KEXP 4
#define EE 1600000
#define EPSV 1e-5f
#define BSHIFT 9
#define BSIZE 512
#define NBUCK 196       // ceil(100000/512)
#define PCHUNK 4096     // edges per block in hist/partition kernels
#define PG ((EE + PCHUNK - 1) / PCHUNK)   // 391
#define SLOTS 64        // hashed stat accumulator slots
#define STAGECAP 12288  // LDS stage entries for bucket_build (48 KB)

typedef __attribute__((ext_vector_type(8))) short bfrag8;
typedef __attribute__((ext_vector_type(16))) float facc16;

__device__ __forceinline__ unsigned short f2bf(float f) {
    unsigned u = __float_as_uint(f);
    return (unsigned short)((u + 0x7fff + ((u >> 16) & 1)) >> 16);
}
__device__ __forceinline__ float bf_lo(unsigned u) { return __uint_as_float(u << 16); }
__device__ __forceinline__ float bf_hi(unsigned u) { return __uint_as_float(u & 0xffff0000u); }

// ---------------- radix pass 1: per-(block,bucket) histogram, no atomics --
__global__ __launch_bounds__(256) void hist_pass(const int* __restrict__ edge,
                                                 int* __restrict__ blockhist, int E) {
    int k = blockIdx.y, bx = blockIdx.x;
    const int* dp = edge + (size_t)k * 2 * E + E;
    __shared__ int hist[NBUCK];
    for (int i = threadIdx.x; i < NBUCK; i += 256) hist[i] = 0;
    __syncthreads();
    int cb = bx * PCHUNK, ce = cb + PCHUNK;
    if (ce > E) ce = E;
    for (int e = cb + (int)threadIdx.x; e < ce; e += 256)
        atomicAdd(&hist[dp[e] >> BSHIFT], 1);
    __syncthreads();
    for (int i = threadIdx.x; i < NBUCK; i += 256)
        blockhist[((size_t)k * PG + bx) * NBUCK + i] = hist[i];
}

// ---------------- radix pass 2: column scan -> per-block bases + bucket
// bases (blockhist overwritten in place with exclusive per-block prefix) ----
__global__ __launch_bounds__(256) void scan_pass(int* __restrict__ blockhist,
                                                 int* __restrict__ bbase,
                                                 int* __restrict__ rowptr,
                                                 int n, int E) {
    int k = blockIdx.x;
    int t = threadIdx.x;
    int running = 0;
    if (t < NBUCK) {
        for (int j = 0; j < PG; j++) {
            size_t idx = ((size_t)k * PG + j) * NBUCK + t;
            int v = blockhist[idx];
            blockhist[idx] = running;
            running += v;
        }
    }
    __shared__ int sd[256];
    sd[t] = (t < NBUCK) ? running : 0;
    __syncthreads();
    for (int o = 1; o < 256; o <<= 1) {
        int x = (t >= o) ? sd[t - o] : 0;
        __syncthreads();
        sd[t] += x;
        __syncthreads();
    }
    if (t < NBUCK) bbase[k * (NBUCK + 1) + t] = sd[t] - running;
    if (t == 0) {
        bbase[k * (NBUCK + 1) + NBUCK] = E;
        rowptr[(size_t)k * (n + 1) + n] = E;
    }
}

// ---------------- radix pass 3: LDS-staged local sort + coalesced dump ----
__global__ __launch_bounds__(256) void partition_pass(const int* __restrict__ edge,
                                                      const int* __restrict__ blockhist,
                                                      const int* __restrict__ bbase,
                                                      unsigned* __restrict__ bstream,
                                                      int E) {
    int k = blockIdx.y, bx = blockIdx.x;
    int t = threadIdx.x;
    __shared__ int hist[NBUCK];        // counts -> cursors
    __shared__ int lofs[NBUCK + 1];    // local exclusive prefix
    __shared__ int gbase[NBUCK];       // global dest base for this block
    __shared__ int tmp[256];
    __shared__ unsigned stage[PCHUNK]; // 16 KB
    for (int i = t; i < NBUCK; i += 256) {
        hist[i] = 0;
        gbase[i] = bbase[k * (NBUCK + 1) + i] + blockhist[((size_t)k * PG + bx) * NBUCK + i];
    }
    __syncthreads();
    const int* sp = edge + (size_t)k * 2 * E;
    const int* dp = sp + E;
    int cb = bx * PCHUNK, ce = cb + PCHUNK;
    if (ce > E) ce = E;
    int cnt = ce - cb;
    for (int e = cb + t; e < ce; e += 256)
        atomicAdd(&hist[dp[e] >> BSHIFT], 1);
    __syncthreads();
    int v = (t < NBUCK) ? hist[t] : 0;
    tmp[t] = v;
    __syncthreads();
    for (int o = 1; o < 256; o <<= 1) {
        int x = (t >= o) ? tmp[t - o] : 0;
        __syncthreads();
        tmp[t] += x;
        __syncthreads();
    }
    if (t < NBUCK) { lofs[t] = tmp[t] - v; hist[t] = tmp[t] - v; }
    if (t == 0) lofs[NBUCK] = cnt;
    __syncthreads();
    for (int e = cb + t; e < ce; e += 256) {
        int s = sp[e];
        int d = dp[e];
        int r = atomicAdd(&hist[d >> BSHIFT], 1);
        stage[r] = ((unsigned)(d & (BSIZE - 1)) << 17) | (unsigned)s;
    }
    __syncthreads();
    unsigned* bs = bstream + (size_t)k * E;
    for (int i = t; i < cnt; i += 256) {
        int lo = 0, hi = NBUCK;
        while (hi - lo > 1) {
            int mid = (lo + hi) >> 1;
            if (lofs[mid] <= i) lo = mid; else hi = mid;
        }
        bs[gbase[lo] + (i - lofs[lo])] = stage[i];
    }
}

// ---------------- per-bucket: degree hist + scan + rowptr + dis + LDS-staged
// node sort + dense coalesced dump (write amp ~1x). ----------------------
__global__ __launch_bounds__(256) void bucket_build(const int* __restrict__ bbase,
                                                    const unsigned* __restrict__ bstream,
                                                    int* __restrict__ rowptr,
                                                    float* __restrict__ dis,
                                                    int* __restrict__ adj,
                                                    int n, int E) {
    int k = blockIdx.y;
    int b = blockIdx.x;
    int nb = b << BSHIFT;
    int t = threadIdx.x;
    __shared__ int hist[BSIZE];
    __shared__ int curx[BSIZE];      // LOCAL cursors (offset within bucket)
    __shared__ int tmp[256];
    __shared__ int stage[STAGECAP];  // 48 KB
    hist[t] = 0;
    hist[t + 256] = 0;
    __syncthreads();
    int beg = bbase[k * (NBUCK + 1) + b];
    int end = bbase[k * (NBUCK + 1) + b + 1];
    int cnt = end - beg;
    const unsigned* bs = bstream + (size_t)k * E;
    for (int p = beg + t; p < end; p += 256) {
        atomicAdd(&hist[bs[p] >> 17], 1);
    }
    __syncthreads();
    int a0 = hist[2 * t], a1 = hist[2 * t + 1];
    tmp[t] = a0 + a1;
    __syncthreads();
    for (int o = 1; o < 256; o <<= 1) {
        int x = (t >= o) ? tmp[t - o] : 0;
        __syncthreads();
        tmp[t] += x;
        __syncthreads();
    }
    int ex = tmp[t] - (a0 + a1);  // exclusive prefix over pairs (local)
    int l0 = ex;
    int l1 = ex + a0;
    curx[2 * t] = l0;
    curx[2 * t + 1] = l1;
    int* rp = rowptr + (size_t)k * (n + 1);
    float* dk = dis + (size_t)k * n;
    int node0 = nb + 2 * t, node1 = nb + 2 * t + 1;
    if (node0 < n) { rp[node0] = beg + l0; dk[node0] = rsqrtf((float)a0 + 2.0f); }
    if (node1 < n) { rp[node1] = beg + l1; dk[node1] = rsqrtf((float)a1 + 2.0f); }
    __syncthreads();
    int* aj = adj + (size_t)k * E;
    for (int p = beg + t; p < end; p += 256) {
        unsigned pk = bs[p];
        int pos = atomicAdd(&curx[pk >> 17], 1);
        int sv = (int)(pk & 0x1FFFFu);
        if (pos < STAGECAP) stage[pos] = sv;      // expected path
        else aj[beg + pos] = sv;                  // pathological overflow
    }
    __syncthreads();
    // dense dump: scalar head to 16B alignment, uint4 body, scalar tail
    int lim = cnt < STAGECAP ? cnt : STAGECAP;
    int head = (4 - (beg & 3)) & 3;
    if (head > lim) head = lim;
    if (t < head) aj[beg + t] = stage[t];
    int nv = (lim - head) >> 2;                   // full uint4 groups
    for (int i = t; i < nv; i += 256) {
        int s4 = head + 4 * i;
        uint4 v = make_uint4((unsigned)stage[s4], (unsigned)stage[s4 + 1],
                             (unsigned)stage[s4 + 2], (unsigned)stage[s4 + 3]);
        *(uint4*)&aj[beg + s4] = v;
    }
    int tail0 = head + 4 * nv;
    for (int i = tail0 + t; i < lim; i += 256) aj[beg + i] = stage[i];
}

// ---------------- convert flatten -> bf16 (once) ----------------
__global__ __launch_bounds__(256) void a2bf_kernel(const float* __restrict__ A,
                                                   unsigned short* __restrict__ abf,
                                                   int n4) {
    int i = blockIdx.x * 256 + threadIdx.x;
    if (i >= n4) return;
    float4 v = ((const float4*)A)[i];
    ushort4 o;
    o.x = f2bf(v.x); o.y = f2bf(v.y); o.z = f2bf(v.z); o.w = f2bf(v.w);
    ((ushort4*)abf)[i] = o;
}

// ---------------- convert + transpose W1 -> Wt[k][col][kk] bf16 ----------
__global__ __launch_bounds__(256) void w2bf_kernel(const float* __restrict__ W1,
                                                   unsigned short* __restrict__ Wt) {
    int k = blockIdx.x;
    for (int idx = threadIdx.x; idx < 64 * 256; idx += 256) {
        int c = idx >> 8;       // col 0..63
        int kk = idx & 255;     // k 0..255
        Wt[(size_t)k * 64 * 256 + c * 256 + kk] = f2bf(W1[(size_t)k * 256 * 64 + kk * 64 + c]);
    }
}

// ---------------- GEMM1 (MFMA): ph1 = dis * (A @ W), bf16 out.  Folding
// dis into the epilogue removes the random dis[s] load AND all per-edge
// multiplies from gather1's inner loop. ----------------------------------
__global__ __launch_bounds__(256) void gemm1_mfma(
    const unsigned short* __restrict__ abf,  // [M,256] bf16
    const unsigned short* __restrict__ Wt,   // [64,256] bf16 (W^T)
    const float* __restrict__ dk,            // [M] dis for this expert
    unsigned short* __restrict__ phbf,       // [M,64] bf16 = dis*h
    int M) {
    __shared__ __align__(16) unsigned short As[64][72];  // [row][k], +8 pad
    __shared__ __align__(16) unsigned short Bs[64][72];  // [col][k]
    int t = threadIdx.x;
    int row0 = blockIdx.x * 64;
    int wid = t >> 6, lane = t & 63;
    int qr = wid >> 1, qc = wid & 1;
    facc16 acc;
    for (int i = 0; i < 16; i++) acc[i] = 0.f;

    for (int kc = 0; kc < 256; kc += 64) {
        for (int i = 0; i < 2; i++) {
            int fid = t + i * 256;    // 0..511
            int r = fid >> 3;
            int o = (fid & 7) * 8;
            int row = row0 + r;
            uint4 v = make_uint4(0u, 0u, 0u, 0u);
            if (row < M) v = *(const uint4*)&abf[(size_t)row * 256 + kc + o];
            *(uint4*)&As[r][o] = v;
        }
        for (int i = 0; i < 2; i++) {
            int fid = t + i * 256;
            int c = fid >> 3;
            int o = (fid & 7) * 8;
            uint4 v = *(const uint4*)&Wt[(size_t)c * 256 + kc + o];
            *(uint4*)&Bs[c][o] = v;
        }
        __syncthreads();
        int arow = qr * 32 + (lane & 31);
        int bcol = qc * 32 + (lane & 31);
        int ko = (lane >> 5) * 8;
        for (int kk = 0; kk < 64; kk += 16) {
            bfrag8 a = *(const bfrag8*)&As[arow][kk + ko];
            bfrag8 b = *(const bfrag8*)&Bs[bcol][kk + ko];
            acc = __builtin_amdgcn_mfma_f32_32x32x16_bf16(a, b, acc, 0, 0, 0);
        }
        __syncthreads();
    }
    int col = qc * 32 + (lane & 31);
    for (int i = 0; i < 16; i++) {
        int rl = (i & 3) + 8 * (i >> 2) + 4 * (lane >> 5);
        int row = row0 + qr * 32 + rl;
        if (row < M) phbf[(size_t)row * 64 + col] = f2bf(dk[row] * acc[i]);
    }
}

// ---------------- GEMM1 fallback (fp32 VALU), dis-folded bf16 out --------
__global__ __launch_bounds__(256) void gemm1_fp32(
    const float* __restrict__ A, const float* __restrict__ W,
    const float* __restrict__ dk,
    unsigned short* __restrict__ phbf, int M) {
    __shared__ __align__(16) float As[64][65];
    __shared__ __align__(16) float Ws[64][68];
    int t = threadIdx.x;
    int row0 = blockIdx.x * 64;
    int tr = t >> 4;
    int tc = t & 15;
    float acc[4][4] = {{0.f}};
    for (int kc = 0; kc < 256; kc += 64) {
        for (int i = 0; i < 4; i++) {
            int fid = t + i * 256;
            int r = fid >> 4;
            int c4 = (fid & 15) << 2;
            int row = row0 + r;
            float4 v = make_float4(0.f, 0.f, 0.f, 0.f);
            if (row < M) v = *(const float4*)&A[(size_t)row * 256 + kc + c4];
            As[r][c4] = v.x; As[r][c4 + 1] = v.y; As[r][c4 + 2] = v.z; As[r][c4 + 3] = v.w;
        }
        for (int i = 0; i < 4; i++) {
            int fid = t + i * 256;
            int r = fid >> 4;
            int c4 = (fid & 15) << 2;
            float4 v = *(const float4*)&W[(size_t)(kc + r) * 64 + c4];
            *(float4*)&Ws[r][c4] = v;
        }
        __syncthreads();
        for (int kk = 0; kk < 64; kk++) {
            float a0 = As[tr * 4 + 0][kk];
            float a1 = As[tr * 4 + 1][kk];
            float a2 = As[tr * 4 + 2][kk];
            float a3 = As[tr * 4 + 3][kk];
            float4 w = *(const float4*)&Ws[kk][tc * 4];
            acc[0][0] += a0 * w.x; acc[0][1] += a0 * w.y; acc[0][2] += a0 * w.z; acc[0][3] += a0 * w.w;
            acc[1][0] += a1 * w.x; acc[1][1] += a1 * w.y; acc[1][2] += a1 * w.z; acc[1][3] += a1 * w.w;
            acc[2][0] += a2 * w.x; acc[2][1] += a2 * w.y; acc[2][2] += a2 * w.z; acc[2][3] += a2 * w.w;
            acc[3][0] += a3 * w.x; acc[3][1] += a3 * w.y; acc[3][2] += a3 * w.z; acc[3][3] += a3 * w.w;
        }
        __syncthreads();
    }
    for (int i = 0; i < 4; i++) {
        int row = row0 + tr * 4 + i;
        if (row >= M) continue;
        float dn = dk[row];
        ushort4 o;
        o.x = f2bf(dn * acc[i][0]); o.y = f2bf(dn * acc[i][1]);
        o.z = f2bf(dn * acc[i][2]); o.w = f2bf(dn * acc[i][3]);
        *(ushort4*)&phbf[(size_t)row * 64 + 4 * tc] = o;
    }
}

// ---------------- gather agg1: wave per node, 4 edges/iter (16-lane
// groups, 8B loads), dis pre-folded so the inner loop is pure adds.
// Fused relu + BN stats (hashed-slot global accumulate). -----------------
__global__ __launch_bounds__(256) void gather1(const int* __restrict__ rowptr,
                                               const int* __restrict__ adj,
                                               const float* __restrict__ dis,
                                               const unsigned short* __restrict__ phbf,
                                               const float* __restrict__ b1,
                                               float* __restrict__ x,
                                               float* __restrict__ accum, int n) {
    __shared__ float ls[4][64];
    __shared__ float lq[4][64];
    ((float*)ls)[threadIdx.x] = 0.f;
    ((float*)lq)[threadIdx.x] = 0.f;
    __syncthreads();
    int w = threadIdx.x >> 6;
    int node = blockIdx.x * 4 + w;
    int lane = threadIdx.x & 63;
    int g = lane >> 4;       // edge group 0..3
    int q = lane & 15;       // channel quad: channels 4q..4q+3
    if (node < n) {
        int beg = rowptr[node], end = rowptr[node + 1];
        float a0 = 0.f, a1 = 0.f, a2 = 0.f, a3 = 0.f;
        for (int j = beg; j < end; j += 4) {
            int jj = j + g;
            if (jj < end) {
                int s = adj[jj];
                uint2 u = *(const uint2*)&phbf[(size_t)s * 64 + 4 * q];
                a0 += bf_lo(u.x);
                a1 += bf_hi(u.x);
                a2 += bf_lo(u.y);
                a3 += bf_hi(u.y);
            }
        }
        // reduce the 4 edge-groups (lanes q, 16+q, 32+q, 48+q)
        a0 += __shfl_xor(a0, 16); a1 += __shfl_xor(a1, 16);
        a2 += __shfl_xor(a2, 16); a3 += __shfl_xor(a3, 16);
        a0 += __shfl_xor(a0, 32); a1 += __shfl_xor(a1, 32);
        a2 += __shfl_xor(a2, 32); a3 += __shfl_xor(a3, 32);
        if (g == 0) {
            float dn = dis[node];
            uint2 us = *(const uint2*)&phbf[(size_t)node * 64 + 4 * q];
            float4 bv = *(const float4*)&b1[4 * q];
            float v0 = dn * (a0 + 2.f * bf_lo(us.x)) + bv.x;
            float v1 = dn * (a1 + 2.f * bf_hi(us.x)) + bv.y;
            float v2 = dn * (a2 + 2.f * bf_lo(us.y)) + bv.z;
            float v3 = dn * (a3 + 2.f * bf_hi(us.y)) + bv.w;
            v0 = fmaxf(v0, 0.f); v1 = fmaxf(v1, 0.f);
            v2 = fmaxf(v2, 0.f); v3 = fmaxf(v3, 0.f);
            *(float4*)&x[(size_t)node * 64 + 4 * q] = make_float4(v0, v1, v2, v3);
            *(float4*)&ls[w][4 * q] = make_float4(v0, v1, v2, v3);
            *(float4*)&lq[w][4 * q] = make_float4(v0 * v0, v1 * v1, v2 * v2, v3 * v3);
        }
    }
    __syncthreads();
    if (threadIdx.x < 64) {
        int c = threadIdx.x;
        float S = ls[0][c] + ls[1][c] + ls[2][c] + ls[3][c];
        float Q = lq[0][c] + lq[1][c] + lq[2][c] + lq[3][c];
        float* slot = accum + (size_t)(blockIdx.x & (SLOTS - 1)) * 128;
        unsafeAtomicAdd(&slot[c], S);
        unsafeAtomicAdd(&slot[64 + c], Q);
    }
}

// ---------------- BN apply + GEMM2 (64 -> 2), stats finalized inline.
// Output is PREMULTIPLIED: ph[node] = dis[node] * (h2 row). --------------
__global__ __launch_bounds__(256) void bn_gemm2(const float* __restrict__ x,
                                                const float* __restrict__ accum,
                                                const float* __restrict__ g,
                                                const float* __restrict__ bt,
                                                const float* __restrict__ W2,
                                                const float* __restrict__ dk,
                                                float* __restrict__ ph, int M) {
    __shared__ float a_s[64], b_s[64];
    int t = threadIdx.x;
    if (t < 64) {
        float S = 0.f, Q = 0.f;
        for (int s = 0; s < SLOTS; s++) {
            S += accum[(size_t)s * 128 + t];
            Q += accum[(size_t)s * 128 + 64 + t];
        }
        float mu = S / (float)M;
        float var = Q / (float)M - mu * mu;
        float istdg = rsqrtf(var + EPSV) * g[t];
        a_s[t] = istdg;
        b_s[t] = bt[t] - mu * istdg;
    }
    __syncthreads();
    int w = t >> 6;
    int c = t & 63;
    float a = a_s[c], b = b_s[c];
    float w20 = W2[c * 2], w21 = W2[c * 2 + 1];
    for (int node = blockIdx.x * 4 + w; node < M; node += gridDim.x * 4) {
        float v = x[(size_t)node * 64 + c] * a + b;
        float p0 = v * w20;
        float p1 = v * w21;
        for (int off = 32; off; off >>= 1) {
            p0 += __shfl_down(p0, off);
            p1 += __shfl_down(p1, off);
        }
        if (c == 0) {
            float dn = dk[node];
            *(float2*)&ph[(size_t)node * 2] = make_float2(dn * p0, dn * p1);
        }
    }
}

// ---------------- gather agg2: thread per node, all experts, XCD-pinned.
// ph = dis*h2 premultiplied -> one 8B random load per edge.  Swizzle
// k=(B&7)>>1 pins each expert's 800KB ph array to 2 XCDs' L2. ------------
__global__ __launch_bounds__(256) void gather2_all(const int* __restrict__ rowptr,
                                                   const int* __restrict__ adj,
                                                   const float* __restrict__ dis,
                                                   const float* __restrict__ phall,
                                                   const float* __restrict__ b2,
                                                   float* __restrict__ agg2,
                                                   int n, int E) {
    int B = blockIdx.x;
    int k = (B & 7) >> 1;                      // expert 0..3 from XCD pair
    int jb = ((B >> 3) << 1) | (B & 1);        // node-block 0..391
    int node = jb * 256 + (int)threadIdx.x;
    if (node >= n) return;
    const int* rp = rowptr + (size_t)k * (n + 1);
    const int* aj = adj + (size_t)k * E;
    const float* ph = phall + (size_t)k * n * 2;
    float dn = dis[(size_t)k * n + node];
    int beg = rp[node], end = rp[node + 1];
    float a0 = 0.f, a1 = 0.f;
    int j = beg;
    for (; j + 2 <= end; j += 2) {
        int s0 = aj[j], s1 = aj[j + 1];
        float2 v0 = *(const float2*)&ph[(size_t)s0 * 2];
        float2 v1 = *(const float2*)&ph[(size_t)s1 * 2];
        a0 += v0.x + v1.x;
        a1 += v0.y + v1.y;
    }
    if (j < end) {
        int s0 = aj[j];
        float2 v0 = *(const float2*)&ph[(size_t)s0 * 2];
        a0 += v0.x;
        a1 += v0.y;
    }
    float2 pn = *(const float2*)&ph[(size_t)node * 2];
    float2 o;
    o.x = dn * (a0 + 2.f * pn.x) + b2[k * 2];
    o.y = dn * (a1 + 2.f * pn.y) + b2[k * 2 + 1];
    *(float2*)&agg2[((size_t)k * n + node) * 2] = o;
}

// ---------------- gating + mixture output ----------------
__global__ __launch_bounds__(256) void final_kernel(const float* __restrict__ moe,
                                                    const float* __restrict__ Wg,
                                                    const float* __restrict__ bg,
                                                    const float* __restrict__ agg2,  // [K][N][2]
                                                    float* __restrict__ out, int M) {
    int n = (int)((blockIdx.x * (size_t)blockDim.x + threadIdx.x) >> 6);
    int lane = threadIdx.x & 63;
    if (n >= M) return;
    float4 mf = *(const float4*)&moe[(size_t)n * 256 + lane * 4];
    const float* wr = &Wg[lane * 16];
    float a0 = mf.x * wr[0] + mf.y * wr[4] + mf.z * wr[8] + mf.w * wr[12];
    float a1 = mf.x * wr[1] + mf.y * wr[5] + mf.z * wr[9] + mf.w * wr[13];
    float a2 = mf.x * wr[2] + mf.y * wr[6] + mf.z * wr[10] + mf.w * wr[14];
    float a3 = mf.x * wr[3] + mf.y * wr[7] + mf.z * wr[11] + mf.w * wr[15];
    for (int mask = 1; mask < 64; mask <<= 1) {
        a0 += __shfl_xor(a0, mask);
        a1 += __shfl_xor(a1, mask);
        a2 += __shfl_xor(a2, mask);
        a3 += __shfl_xor(a3, mask);
    }
    if (lane == 0) {
        float gl[4] = {a0 + bg[0], a1 + bg[1], a2 + bg[2], a3 + bg[3]};
        float m = fmaxf(fmaxf(gl[0], gl[1]), fmaxf(gl[2], gl[3]));
        float w[4];
        float wsum = 0.f;
        for (int kk = 0; kk < 4; kk++) { w[kk] = expf(gl[kk] - m); wsum += w[kk]; }
        float o0 = 0.f, o1 = 0.f, q0 = 0.f, q1 = 0.f;
        for (int kk = 0; kk < 4; kk++) {
            float l0 = agg2[((size_t)kk * M + n) * 2];
            float l1 = agg2[((size_t)kk * M + n) * 2 + 1];
            float mm = fmaxf(l0, l1);
            float lse = mm + logf(expf(l0 - mm) + expf(l1 - mm));
            float lp0 = l0 - lse, lp1 = l1 - lse;
            float wk = w[kk] / wsum;
            o0 += wk * lp0; o1 += wk * lp1;
            q0 += wk * expf(lp0); q1 += wk * expf(lp1);
        }
        out[(size_t)n * 2] = o0;
        out[(size_t)n * 2 + 1] = o1;
        out[(size_t)2 * M + n * 2] = q0;
        out[(size_t)2 * M + n * 2 + 1] = q1;
    }
}

extern "C" void kernel_launch(void* const* d_in, const int* in_sizes, int n_in,
                              void* d_out, int out_size, void* d_ws, size_t ws_size,
                              hipStream_t stream) {
    const float* flatten = (const float*)d_in[0];
    const float* moe     = (const float*)d_in[1];
    const int*   edge    = (const int*)d_in[2];   // [K][2][E]
    const float* W1      = (const float*)d_in[3]; // [K][256][64]
    const float* b1      = (const float*)d_in[4]; // [K][64]
    const float* gamma   = (const float*)d_in[5];
    const float* beta    = (const float*)d_in[6];
    const float* W2      = (const float*)d_in[7]; // [K][64][2]
    const float* b2      = (const float*)d_in[8]; // [K][2]
    const float* Wg      = (const float*)d_in[9]; // [256][4]
    const float* bg      = (const float*)d_in[10];
    float* out = (float*)d_out;

    const int N = NN, E = EE, K = KEXP;

    char* ws = (char*)d_ws;
    size_t off = 0;
    auto alloc = [&](size_t bytes) -> void* {
        void* p = (void*)(ws + off);
        off += (bytes + 255) & ~(size_t)255;
        return p;
    };
    int*   rowptr    = (int*)alloc((size_t)K * (N + 1) * 4);
    float* dis       = (float*)alloc((size_t)K * N * 4);
    int*   blockhist = (int*)alloc((size_t)K * PG * NBUCK * 4);
    int*   bbase     = (int*)alloc((size_t)K * (NBUCK + 1) * 4);
    int*   adj       = (int*)alloc((size_t)K * E * 4);
    unsigned short* hbf = (unsigned short*)alloc((size_t)N * 64 * 2);
    float* x         = (float*)alloc((size_t)N * 64 * 4);
    float* h2all     = (float*)alloc((size_t)K * N * 2 * 4);
    float* agg2      = (float*)alloc((size_t)K * N * 2 * 4);
    float* accum     = (float*)alloc((size_t)K * SLOTS * 128 * 4);
    size_t base_need = off;
    unsigned short* abf = (unsigned short*)alloc((size_t)N * 256 * 2);
    unsigned short* Wt  = (unsigned short*)alloc((size_t)K * 64 * 256 * 2);
    size_t mfma_need = off;
    (void)in_sizes; (void)n_in; (void)out_size; (void)base_need;
    bool use_mfma = (ws_size >= mfma_need);

    // bstream (K*E*4 = 25.6 MB) aliases hbf+x (12.8+25.6 MB contiguous):
    // only used in the build phase, before gemm1/gather1 write hbf/x.
    unsigned* bstream = (unsigned*)hbf;

    // ---- batched CSR build: atomic-free 3-pass bucket radix sort ----
    hipMemsetAsync(accum, 0, (size_t)K * SLOTS * 128 * 4, stream);
    hist_pass<<<dim3(PG, K), 256, 0, stream>>>(edge, blockhist, E);
    scan_pass<<<K, 256, 0, stream>>>(blockhist, bbase, rowptr, N, E);
    partition_pass<<<dim3(PG, K), 256, 0, stream>>>(edge, blockhist, bbase, bstream, E);
    bucket_build<<<dim3(NBUCK, K), 256, 0, stream>>>(bbase, bstream, rowptr, dis, adj, N, E);

    if (use_mfma) {
        a2bf_kernel<<<(N * 256 / 4 + 255) / 256, 256, 0, stream>>>(flatten, abf, N * 256 / 4);
        w2bf_kernel<<<K, 256, 0, stream>>>(W1, Wt);
    }

    // ---- per-expert pipeline ----
    for (int k = 0; k < K; k++) {
        const int* rp = rowptr + (size_t)k * (N + 1);
        const int* aj = adj + (size_t)k * E;
        const float* dk = dis + (size_t)k * N;
        float* ak = accum + (size_t)k * SLOTS * 128;
        if (use_mfma) {
            gemm1_mfma<<<(N + 63) / 64, 256, 0, stream>>>(
                abf, Wt + (size_t)k * 64 * 256, dk, hbf, N);
        } else {
            gemm1_fp32<<<(N + 63) / 64, 256, 0, stream>>>(
                flatten, W1 + (size_t)k * 256 * 64, dk, hbf, N);
        }
        gather1<<<(N + 3) / 4, 256, 0, stream>>>(
            rp, aj, dk, hbf, b1 + (size_t)k * 64, x, ak, N);
        bn_gemm2<<<1024, 256, 0, stream>>>(
            x, ak, gamma + (size_t)k * 64, beta + (size_t)k * 64,
            W2 + (size_t)k * 128, dk, h2all + (size_t)k * N * 2, N);
    }
    // 1568 = 8 XCDs x 196 slots; swizzled (expert, node-block) decode inside
    gather2_all<<<1568, 256, 0, stream>>>(
        rowptr, adj, dis, h2all, b2, agg2, N, E);
    final_kernel<<<(int)(((size_t)N * 64 + 255) / 256), 256, 0, stream>>>(
        moe, Wg, bg, agg2, out, N);
}

// Round 4
// 834.926 us; speedup vs baseline: 1.0804x; 1.0804x over previous
//
#include <hip/hip_runtime.h>
#include <math.h>

#define NN 100000
#define KEXP 4
#define EE 1600000
#define EPSV 1e-5f
#define BSHIFT 9
#define BSIZE 512
#define NBUCK 196       // ceil(100000/512)
#define PCHUNK 4096     // edges per block in hist/partition kernels
#define PG ((EE + PCHUNK - 1) / PCHUNK)   // 391
#define SLOTS 64        // hashed stat accumulator slots
#define STAGECAP 12288  // LDS stage entries for bucket_build (48 KB)

typedef __attribute__((ext_vector_type(8))) short bfrag8;
typedef __attribute__((ext_vector_type(16))) float facc16;

__device__ __forceinline__ unsigned short f2bf(float f) {
    unsigned u = __float_as_uint(f);
    return (unsigned short)((u + 0x7fff + ((u >> 16) & 1)) >> 16);
}
__device__ __forceinline__ float bf_lo(unsigned u) { return __uint_as_float(u << 16); }
__device__ __forceinline__ float bf_hi(unsigned u) { return __uint_as_float(u & 0xffff0000u); }

// ---------------- radix pass 1: per-(block,bucket) histogram, no atomics --
__global__ __launch_bounds__(256) void hist_pass(const int* __restrict__ edge,
                                                 int* __restrict__ blockhist, int E) {
    int k = blockIdx.y, bx = blockIdx.x;
    const int* dp = edge + (size_t)k * 2 * E + E;
    __shared__ int hist[NBUCK];
    for (int i = threadIdx.x; i < NBUCK; i += 256) hist[i] = 0;
    __syncthreads();
    int cb = bx * PCHUNK, ce = cb + PCHUNK;
    if (ce > E) ce = E;
    for (int e = cb + (int)threadIdx.x; e < ce; e += 256)
        atomicAdd(&hist[dp[e] >> BSHIFT], 1);
    __syncthreads();
    for (int i = threadIdx.x; i < NBUCK; i += 256)
        blockhist[((size_t)k * PG + bx) * NBUCK + i] = hist[i];
}

// ---------------- radix pass 2: column scan -> per-block bases + bucket
// bases (blockhist overwritten in place with exclusive per-block prefix) ----
__global__ __launch_bounds__(256) void scan_pass(int* __restrict__ blockhist,
                                                 int* __restrict__ bbase,
                                                 int* __restrict__ rowptr,
                                                 int n, int E) {
    int k = blockIdx.x;
    int t = threadIdx.x;
    int running = 0;
    if (t < NBUCK) {
        for (int j = 0; j < PG; j++) {
            size_t idx = ((size_t)k * PG + j) * NBUCK + t;
            int v = blockhist[idx];
            blockhist[idx] = running;
            running += v;
        }
    }
    __shared__ int sd[256];
    sd[t] = (t < NBUCK) ? running : 0;
    __syncthreads();
    for (int o = 1; o < 256; o <<= 1) {
        int x = (t >= o) ? sd[t - o] : 0;
        __syncthreads();
        sd[t] += x;
        __syncthreads();
    }
    if (t < NBUCK) bbase[k * (NBUCK + 1) + t] = sd[t] - running;
    if (t == 0) {
        bbase[k * (NBUCK + 1) + NBUCK] = E;
        rowptr[(size_t)k * (n + 1) + n] = E;
    }
}

// ---------------- radix pass 3: LDS-staged local sort + coalesced dump ----
__global__ __launch_bounds__(256) void partition_pass(const int* __restrict__ edge,
                                                      const int* __restrict__ blockhist,
                                                      const int* __restrict__ bbase,
                                                      unsigned* __restrict__ bstream,
                                                      int E) {
    int k = blockIdx.y, bx = blockIdx.x;
    int t = threadIdx.x;
    __shared__ int hist[NBUCK];        // counts -> cursors
    __shared__ int lofs[NBUCK + 1];    // local exclusive prefix
    __shared__ int gbase[NBUCK];       // global dest base for this block
    __shared__ int tmp[256];
    __shared__ unsigned stage[PCHUNK]; // 16 KB
    for (int i = t; i < NBUCK; i += 256) {
        hist[i] = 0;
        gbase[i] = bbase[k * (NBUCK + 1) + i] + blockhist[((size_t)k * PG + bx) * NBUCK + i];
    }
    __syncthreads();
    const int* sp = edge + (size_t)k * 2 * E;
    const int* dp = sp + E;
    int cb = bx * PCHUNK, ce = cb + PCHUNK;
    if (ce > E) ce = E;
    int cnt = ce - cb;
    for (int e = cb + t; e < ce; e += 256)
        atomicAdd(&hist[dp[e] >> BSHIFT], 1);
    __syncthreads();
    int v = (t < NBUCK) ? hist[t] : 0;
    tmp[t] = v;
    __syncthreads();
    for (int o = 1; o < 256; o <<= 1) {
        int x = (t >= o) ? tmp[t - o] : 0;
        __syncthreads();
        tmp[t] += x;
        __syncthreads();
    }
    if (t < NBUCK) { lofs[t] = tmp[t] - v; hist[t] = tmp[t] - v; }
    if (t == 0) lofs[NBUCK] = cnt;
    __syncthreads();
    for (int e = cb + t; e < ce; e += 256) {
        int s = sp[e];
        int d = dp[e];
        int r = atomicAdd(&hist[d >> BSHIFT], 1);
        stage[r] = ((unsigned)(d & (BSIZE - 1)) << 17) | (unsigned)s;
    }
    __syncthreads();
    unsigned* bs = bstream + (size_t)k * E;
    for (int i = t; i < cnt; i += 256) {
        int lo = 0, hi = NBUCK;
        while (hi - lo > 1) {
            int mid = (lo + hi) >> 1;
            if (lofs[mid] <= i) lo = mid; else hi = mid;
        }
        bs[gbase[lo] + (i - lofs[lo])] = stage[i];
    }
}

// ---------------- per-bucket: degree hist + scan + rowptr + dis + LDS-staged
// node sort + dense coalesced dump (write amp ~1x). ----------------------
__global__ __launch_bounds__(256) void bucket_build(const int* __restrict__ bbase,
                                                    const unsigned* __restrict__ bstream,
                                                    int* __restrict__ rowptr,
                                                    float* __restrict__ dis,
                                                    int* __restrict__ adj,
                                                    int n, int E) {
    int k = blockIdx.y;
    int b = blockIdx.x;
    int nb = b << BSHIFT;
    int t = threadIdx.x;
    __shared__ int hist[BSIZE];
    __shared__ int curx[BSIZE];      // LOCAL cursors (offset within bucket)
    __shared__ int tmp[256];
    __shared__ int stage[STAGECAP];  // 48 KB
    hist[t] = 0;
    hist[t + 256] = 0;
    __syncthreads();
    int beg = bbase[k * (NBUCK + 1) + b];
    int end = bbase[k * (NBUCK + 1) + b + 1];
    int cnt = end - beg;
    const unsigned* bs = bstream + (size_t)k * E;
    for (int p = beg + t; p < end; p += 256) {
        atomicAdd(&hist[bs[p] >> 17], 1);
    }
    __syncthreads();
    int a0 = hist[2 * t], a1 = hist[2 * t + 1];
    tmp[t] = a0 + a1;
    __syncthreads();
    for (int o = 1; o < 256; o <<= 1) {
        int x = (t >= o) ? tmp[t - o] : 0;
        __syncthreads();
        tmp[t] += x;
        __syncthreads();
    }
    int ex = tmp[t] - (a0 + a1);  // exclusive prefix over pairs (local)
    int l0 = ex;
    int l1 = ex + a0;
    curx[2 * t] = l0;
    curx[2 * t + 1] = l1;
    int* rp = rowptr + (size_t)k * (n + 1);
    float* dk = dis + (size_t)k * n;
    int node0 = nb + 2 * t, node1 = nb + 2 * t + 1;
    if (node0 < n) { rp[node0] = beg + l0; dk[node0] = rsqrtf((float)a0 + 2.0f); }
    if (node1 < n) { rp[node1] = beg + l1; dk[node1] = rsqrtf((float)a1 + 2.0f); }
    __syncthreads();
    int* aj = adj + (size_t)k * E;
    for (int p = beg + t; p < end; p += 256) {
        unsigned pk = bs[p];
        int pos = atomicAdd(&curx[pk >> 17], 1);
        int sv = (int)(pk & 0x1FFFFu);
        if (pos < STAGECAP) stage[pos] = sv;      // expected path
        else aj[beg + pos] = sv;                  // pathological overflow
    }
    __syncthreads();
    // dense dump: scalar head to 16B alignment, uint4 body, scalar tail
    int lim = cnt < STAGECAP ? cnt : STAGECAP;
    int head = (4 - (beg & 3)) & 3;
    if (head > lim) head = lim;
    if (t < head) aj[beg + t] = stage[t];
    int nv = (lim - head) >> 2;                   // full uint4 groups
    for (int i = t; i < nv; i += 256) {
        int s4 = head + 4 * i;
        uint4 v = make_uint4((unsigned)stage[s4], (unsigned)stage[s4 + 1],
                             (unsigned)stage[s4 + 2], (unsigned)stage[s4 + 3]);
        *(uint4*)&aj[beg + s4] = v;
    }
    int tail0 = head + 4 * nv;
    for (int i = tail0 + t; i < lim; i += 256) aj[beg + i] = stage[i];
}

// ---------------- convert flatten -> bf16 (once) ----------------
__global__ __launch_bounds__(256) void a2bf_kernel(const float* __restrict__ A,
                                                   unsigned short* __restrict__ abf,
                                                   int n4) {
    int i = blockIdx.x * 256 + threadIdx.x;
    if (i >= n4) return;
    float4 v = ((const float4*)A)[i];
    ushort4 o;
    o.x = f2bf(v.x); o.y = f2bf(v.y); o.z = f2bf(v.z); o.w = f2bf(v.w);
    ((ushort4*)abf)[i] = o;
}

// ---------------- convert + transpose W1 -> Wt[k][col][kk] bf16 ----------
__global__ __launch_bounds__(256) void w2bf_kernel(const float* __restrict__ W1,
                                                   unsigned short* __restrict__ Wt) {
    int k = blockIdx.x;
    for (int idx = threadIdx.x; idx < 64 * 256; idx += 256) {
        int c = idx >> 8;       // col 0..63
        int kk = idx & 255;     // k 0..255
        Wt[(size_t)k * 64 * 256 + c * 256 + kk] = f2bf(W1[(size_t)k * 256 * 64 + kk * 64 + c]);
    }
}

// ---------------- GEMM1 (MFMA): ph1 = dis * (A @ W), bf16 out ------------
__global__ __launch_bounds__(256) void gemm1_mfma(
    const unsigned short* __restrict__ abf,  // [M,256] bf16
    const unsigned short* __restrict__ Wt,   // [64,256] bf16 (W^T)
    const float* __restrict__ dk,            // [M] dis for this expert
    unsigned short* __restrict__ phbf,       // [M,64] bf16 = dis*h
    int M) {
    __shared__ __align__(16) unsigned short As[64][72];  // [row][k], +8 pad
    __shared__ __align__(16) unsigned short Bs[64][72];  // [col][k]
    int t = threadIdx.x;
    int row0 = blockIdx.x * 64;
    int wid = t >> 6, lane = t & 63;
    int qr = wid >> 1, qc = wid & 1;
    facc16 acc;
    for (int i = 0; i < 16; i++) acc[i] = 0.f;

    for (int kc = 0; kc < 256; kc += 64) {
        for (int i = 0; i < 2; i++) {
            int fid = t + i * 256;    // 0..511
            int r = fid >> 3;
            int o = (fid & 7) * 8;
            int row = row0 + r;
            uint4 v = make_uint4(0u, 0u, 0u, 0u);
            if (row < M) v = *(const uint4*)&abf[(size_t)row * 256 + kc + o];
            *(uint4*)&As[r][o] = v;
        }
        for (int i = 0; i < 2; i++) {
            int fid = t + i * 256;
            int c = fid >> 3;
            int o = (fid & 7) * 8;
            uint4 v = *(const uint4*)&Wt[(size_t)c * 256 + kc + o];
            *(uint4*)&Bs[c][o] = v;
        }
        __syncthreads();
        int arow = qr * 32 + (lane & 31);
        int bcol = qc * 32 + (lane & 31);
        int ko = (lane >> 5) * 8;
        for (int kk = 0; kk < 64; kk += 16) {
            bfrag8 a = *(const bfrag8*)&As[arow][kk + ko];
            bfrag8 b = *(const bfrag8*)&Bs[bcol][kk + ko];
            acc = __builtin_amdgcn_mfma_f32_32x32x16_bf16(a, b, acc, 0, 0, 0);
        }
        __syncthreads();
    }
    int col = qc * 32 + (lane & 31);
    for (int i = 0; i < 16; i++) {
        int rl = (i & 3) + 8 * (i >> 2) + 4 * (lane >> 5);
        int row = row0 + qr * 32 + rl;
        if (row < M) phbf[(size_t)row * 64 + col] = f2bf(dk[row] * acc[i]);
    }
}

// ---------------- GEMM1 fallback (fp32 VALU), dis-folded bf16 out --------
__global__ __launch_bounds__(256) void gemm1_fp32(
    const float* __restrict__ A, const float* __restrict__ W,
    const float* __restrict__ dk,
    unsigned short* __restrict__ phbf, int M) {
    __shared__ __align__(16) float As[64][65];
    __shared__ __align__(16) float Ws[64][68];
    int t = threadIdx.x;
    int row0 = blockIdx.x * 64;
    int tr = t >> 4;
    int tc = t & 15;
    float acc[4][4] = {{0.f}};
    for (int kc = 0; kc < 256; kc += 64) {
        for (int i = 0; i < 4; i++) {
            int fid = t + i * 256;
            int r = fid >> 4;
            int c4 = (fid & 15) << 2;
            int row = row0 + r;
            float4 v = make_float4(0.f, 0.f, 0.f, 0.f);
            if (row < M) v = *(const float4*)&A[(size_t)row * 256 + kc + c4];
            As[r][c4] = v.x; As[r][c4 + 1] = v.y; As[r][c4 + 2] = v.z; As[r][c4 + 3] = v.w;
        }
        for (int i = 0; i < 4; i++) {
            int fid = t + i * 256;
            int r = fid >> 4;
            int c4 = (fid & 15) << 2;
            float4 v = *(const float4*)&W[(size_t)(kc + r) * 64 + c4];
            *(float4*)&Ws[r][c4] = v;
        }
        __syncthreads();
        for (int kk = 0; kk < 64; kk++) {
            float a0 = As[tr * 4 + 0][kk];
            float a1 = As[tr * 4 + 1][kk];
            float a2 = As[tr * 4 + 2][kk];
            float a3 = As[tr * 4 + 3][kk];
            float4 w = *(const float4*)&Ws[kk][tc * 4];
            acc[0][0] += a0 * w.x; acc[0][1] += a0 * w.y; acc[0][2] += a0 * w.z; acc[0][3] += a0 * w.w;
            acc[1][0] += a1 * w.x; acc[1][1] += a1 * w.y; acc[1][2] += a1 * w.z; acc[1][3] += a1 * w.w;
            acc[2][0] += a2 * w.x; acc[2][1] += a2 * w.y; acc[2][2] += a2 * w.z; acc[2][3] += a2 * w.w;
            acc[3][0] += a3 * w.x; acc[3][1] += a3 * w.y; acc[3][2] += a3 * w.z; acc[3][3] += a3 * w.w;
        }
        __syncthreads();
    }
    for (int i = 0; i < 4; i++) {
        int row = row0 + tr * 4 + i;
        if (row >= M) continue;
        float dn = dk[row];
        ushort4 o;
        o.x = f2bf(dn * acc[i][0]); o.y = f2bf(dn * acc[i][1]);
        o.z = f2bf(dn * acc[i][2]); o.w = f2bf(dn * acc[i][3]);
        *(ushort4*)&phbf[(size_t)row * 64 + 4 * tc] = o;
    }
}

// ---------------- gather agg1: wave per node, 8 rows in flight (4 edge
// groups x 2-unroll, dual accumulators), dis pre-folded -> inner loop is
// pure adds.  Fused relu + BN stats (hashed-slot global accumulate). -----
__global__ __launch_bounds__(256) void gather1(const int* __restrict__ rowptr,
                                               const int* __restrict__ adj,
                                               const float* __restrict__ dis,
                                               const unsigned short* __restrict__ phbf,
                                               const float* __restrict__ b1,
                                               float* __restrict__ x,
                                               float* __restrict__ accum, int n) {
    __shared__ float ls[4][64];
    __shared__ float lq[4][64];
    ((float*)ls)[threadIdx.x] = 0.f;
    ((float*)lq)[threadIdx.x] = 0.f;
    __syncthreads();
    int w = threadIdx.x >> 6;
    int node = blockIdx.x * 4 + w;
    int lane = threadIdx.x & 63;
    int g = lane >> 4;       // edge group 0..3
    int q = lane & 15;       // channel quad: channels 4q..4q+3
    if (node < n) {
        int beg = rowptr[node], end = rowptr[node + 1];
        float a0 = 0.f, a1 = 0.f, a2 = 0.f, a3 = 0.f;
        float c0 = 0.f, c1 = 0.f, c2 = 0.f, c3 = 0.f;
        int j = beg;
        for (; j + 8 <= end; j += 8) {
            int s0 = adj[j + g];
            int s1 = adj[j + 4 + g];
            uint2 u0 = *(const uint2*)&phbf[(size_t)s0 * 64 + 4 * q];
            uint2 u1 = *(const uint2*)&phbf[(size_t)s1 * 64 + 4 * q];
            a0 += bf_lo(u0.x); a1 += bf_hi(u0.x);
            a2 += bf_lo(u0.y); a3 += bf_hi(u0.y);
            c0 += bf_lo(u1.x); c1 += bf_hi(u1.x);
            c2 += bf_lo(u1.y); c3 += bf_hi(u1.y);
        }
        for (; j < end; j += 4) {
            int jj = j + g;
            if (jj < end) {
                int s = adj[jj];
                uint2 u = *(const uint2*)&phbf[(size_t)s * 64 + 4 * q];
                a0 += bf_lo(u.x); a1 += bf_hi(u.x);
                a2 += bf_lo(u.y); a3 += bf_hi(u.y);
            }
        }
        a0 += c0; a1 += c1; a2 += c2; a3 += c3;
        // reduce the 4 edge-groups (lanes q, 16+q, 32+q, 48+q)
        a0 += __shfl_xor(a0, 16); a1 += __shfl_xor(a1, 16);
        a2 += __shfl_xor(a2, 16); a3 += __shfl_xor(a3, 16);
        a0 += __shfl_xor(a0, 32); a1 += __shfl_xor(a1, 32);
        a2 += __shfl_xor(a2, 32); a3 += __shfl_xor(a3, 32);
        if (g == 0) {
            float dn = dis[node];
            uint2 us = *(const uint2*)&phbf[(size_t)node * 64 + 4 * q];
            float4 bv = *(const float4*)&b1[4 * q];
            float v0 = dn * (a0 + 2.f * bf_lo(us.x)) + bv.x;
            float v1 = dn * (a1 + 2.f * bf_hi(us.x)) + bv.y;
            float v2 = dn * (a2 + 2.f * bf_lo(us.y)) + bv.z;
            float v3 = dn * (a3 + 2.f * bf_hi(us.y)) + bv.w;
            v0 = fmaxf(v0, 0.f); v1 = fmaxf(v1, 0.f);
            v2 = fmaxf(v2, 0.f); v3 = fmaxf(v3, 0.f);
            *(float4*)&x[(size_t)node * 64 + 4 * q] = make_float4(v0, v1, v2, v3);
            *(float4*)&ls[w][4 * q] = make_float4(v0, v1, v2, v3);
            *(float4*)&lq[w][4 * q] = make_float4(v0 * v0, v1 * v1, v2 * v2, v3 * v3);
        }
    }
    __syncthreads();
    if (threadIdx.x < 64) {
        int c = threadIdx.x;
        float S = ls[0][c] + ls[1][c] + ls[2][c] + ls[3][c];
        float Q = lq[0][c] + lq[1][c] + lq[2][c] + lq[3][c];
        float* slot = accum + (size_t)(blockIdx.x & (SLOTS - 1)) * 128;
        unsafeAtomicAdd(&slot[c], S);
        unsafeAtomicAdd(&slot[64 + c], Q);
    }
}

// ---------------- BN apply + GEMM2 (64 -> 2), stats finalized inline.
// Output is PREMULTIPLIED: ph[node] = dis[node] * (h2 row). --------------
__global__ __launch_bounds__(256) void bn_gemm2(const float* __restrict__ x,
                                                const float* __restrict__ accum,
                                                const float* __restrict__ g,
                                                const float* __restrict__ bt,
                                                const float* __restrict__ W2,
                                                const float* __restrict__ dk,
                                                float* __restrict__ ph, int M) {
    __shared__ float a_s[64], b_s[64];
    int t = threadIdx.x;
    if (t < 64) {
        float S = 0.f, Q = 0.f;
        for (int s = 0; s < SLOTS; s++) {
            S += accum[(size_t)s * 128 + t];
            Q += accum[(size_t)s * 128 + 64 + t];
        }
        float mu = S / (float)M;
        float var = Q / (float)M - mu * mu;
        float istdg = rsqrtf(var + EPSV) * g[t];
        a_s[t] = istdg;
        b_s[t] = bt[t] - mu * istdg;
    }
    __syncthreads();
    int w = t >> 6;
    int c = t & 63;
    float a = a_s[c], b = b_s[c];
    float w20 = W2[c * 2], w21 = W2[c * 2 + 1];
    for (int node = blockIdx.x * 4 + w; node < M; node += gridDim.x * 4) {
        float v = x[(size_t)node * 64 + c] * a + b;
        float p0 = v * w20;
        float p1 = v * w21;
        for (int off = 32; off; off >>= 1) {
            p0 += __shfl_down(p0, off);
            p1 += __shfl_down(p1, off);
        }
        if (c == 0) {
            float dn = dk[node];
            *(float2*)&ph[(size_t)node * 2] = make_float2(dn * p0, dn * p1);
        }
    }
}

// ---------------- gather agg2: thread per node, all experts, XCD-pinned --
__global__ __launch_bounds__(256) void gather2_all(const int* __restrict__ rowptr,
                                                   const int* __restrict__ adj,
                                                   const float* __restrict__ dis,
                                                   const float* __restrict__ phall,
                                                   const float* __restrict__ b2,
                                                   float* __restrict__ agg2,
                                                   int n, int E) {
    int B = blockIdx.x;
    int k = (B & 7) >> 1;                      // expert 0..3 from XCD pair
    int jb = ((B >> 3) << 1) | (B & 1);        // node-block 0..391
    int node = jb * 256 + (int)threadIdx.x;
    if (node >= n) return;
    const int* rp = rowptr + (size_t)k * (n + 1);
    const int* aj = adj + (size_t)k * E;
    const float* ph = phall + (size_t)k * n * 2;
    float dn = dis[(size_t)k * n + node];
    int beg = rp[node], end = rp[node + 1];
    float a0 = 0.f, a1 = 0.f;
    int j = beg;
    for (; j + 2 <= end; j += 2) {
        int s0 = aj[j], s1 = aj[j + 1];
        float2 v0 = *(const float2*)&ph[(size_t)s0 * 2];
        float2 v1 = *(const float2*)&ph[(size_t)s1 * 2];
        a0 += v0.x + v1.x;
        a1 += v0.y + v1.y;
    }
    if (j < end) {
        int s0 = aj[j];
        float2 v0 = *(const float2*)&ph[(size_t)s0 * 2];
        a0 += v0.x;
        a1 += v0.y;
    }
    float2 pn = *(const float2*)&ph[(size_t)node * 2];
    float2 o;
    o.x = dn * (a0 + 2.f * pn.x) + b2[k * 2];
    o.y = dn * (a1 + 2.f * pn.y) + b2[k * 2 + 1];
    *(float2*)&agg2[((size_t)k * n + node) * 2] = o;
}

// ---------------- gating: wave-per-node matvec + softmax -> w[n][4] ------
// (the heavy lse/logp epilogue moved to mix_kernel, thread-per-node)
__global__ __launch_bounds__(256) void gate_kernel(const float* __restrict__ moe,
                                                   const float* __restrict__ Wg,
                                                   const float* __restrict__ bg,
                                                   float* __restrict__ wbuf, int M) {
    int n = (int)((blockIdx.x * (size_t)blockDim.x + threadIdx.x) >> 6);
    int lane = threadIdx.x & 63;
    if (n >= M) return;
    float4 mf = *(const float4*)&moe[(size_t)n * 256 + lane * 4];
    const float* wr = &Wg[lane * 16];
    float a0 = mf.x * wr[0] + mf.y * wr[4] + mf.z * wr[8] + mf.w * wr[12];
    float a1 = mf.x * wr[1] + mf.y * wr[5] + mf.z * wr[9] + mf.w * wr[13];
    float a2 = mf.x * wr[2] + mf.y * wr[6] + mf.z * wr[10] + mf.w * wr[14];
    float a3 = mf.x * wr[3] + mf.y * wr[7] + mf.z * wr[11] + mf.w * wr[15];
    for (int mask = 1; mask < 64; mask <<= 1) {
        a0 += __shfl_xor(a0, mask);
        a1 += __shfl_xor(a1, mask);
        a2 += __shfl_xor(a2, mask);
        a3 += __shfl_xor(a3, mask);
    }
    if (lane == 0) {
        float g0 = a0 + bg[0], g1 = a1 + bg[1], g2 = a2 + bg[2], g3 = a3 + bg[3];
        float m = fmaxf(fmaxf(g0, g1), fmaxf(g2, g3));
        float w0 = expf(g0 - m), w1 = expf(g1 - m), w2 = expf(g2 - m), w3 = expf(g3 - m);
        float inv = 1.f / (w0 + w1 + w2 + w3);
        *(float4*)&wbuf[(size_t)n * 4] =
            make_float4(w0 * inv, w1 * inv, w2 * inv, w3 * inv);
    }
}

// ---------------- mixture epilogue: THREAD per node (all lanes busy on the
// transcendentals; coalesced agg2/out access) ----------------------------
__global__ __launch_bounds__(256) void mix_kernel(const float* __restrict__ wbuf,
                                                  const float* __restrict__ agg2,  // [K][N][2]
                                                  float* __restrict__ out, int M) {
    int n = blockIdx.x * 256 + threadIdx.x;
    if (n >= M) return;
    float4 wv = *(const float4*)&wbuf[(size_t)n * 4];
    float wk[4] = {wv.x, wv.y, wv.z, wv.w};
    float o0 = 0.f, o1 = 0.f, q0 = 0.f, q1 = 0.f;
    for (int kk = 0; kk < 4; kk++) {
        float2 l = *(const float2*)&agg2[((size_t)kk * M + n) * 2];
        float mm = fmaxf(l.x, l.y);
        float lse = mm + logf(expf(l.x - mm) + expf(l.y - mm));
        float lp0 = l.x - lse, lp1 = l.y - lse;
        o0 += wk[kk] * lp0; o1 += wk[kk] * lp1;
        q0 += wk[kk] * expf(lp0); q1 += wk[kk] * expf(lp1);
    }
    *(float2*)&out[(size_t)n * 2] = make_float2(o0, o1);
    *(float2*)&out[(size_t)2 * M + n * 2] = make_float2(q0, q1);
}

extern "C" void kernel_launch(void* const* d_in, const int* in_sizes, int n_in,
                              void* d_out, int out_size, void* d_ws, size_t ws_size,
                              hipStream_t stream) {
    const float* flatten = (const float*)d_in[0];
    const float* moe     = (const float*)d_in[1];
    const int*   edge    = (const int*)d_in[2];   // [K][2][E]
    const float* W1      = (const float*)d_in[3]; // [K][256][64]
    const float* b1      = (const float*)d_in[4]; // [K][64]
    const float* gamma   = (const float*)d_in[5];
    const float* beta    = (const float*)d_in[6];
    const float* W2      = (const float*)d_in[7]; // [K][64][2]
    const float* b2      = (const float*)d_in[8]; // [K][2]
    const float* Wg      = (const float*)d_in[9]; // [256][4]
    const float* bg      = (const float*)d_in[10];
    float* out = (float*)d_out;

    const int N = NN, E = EE, K = KEXP;

    char* ws = (char*)d_ws;
    size_t off = 0;
    auto alloc = [&](size_t bytes) -> void* {
        void* p = (void*)(ws + off);
        off += (bytes + 255) & ~(size_t)255;
        return p;
    };
    int*   rowptr    = (int*)alloc((size_t)K * (N + 1) * 4);
    float* dis       = (float*)alloc((size_t)K * N * 4);
    int*   blockhist = (int*)alloc((size_t)K * PG * NBUCK * 4);
    int*   bbase     = (int*)alloc((size_t)K * (NBUCK + 1) * 4);
    int*   adj       = (int*)alloc((size_t)K * E * 4);
    unsigned short* hbf = (unsigned short*)alloc((size_t)N * 64 * 2);
    float* x         = (float*)alloc((size_t)N * 64 * 4);
    float* h2all     = (float*)alloc((size_t)K * N * 2 * 4);
    float* agg2      = (float*)alloc((size_t)K * N * 2 * 4);
    float* accum     = (float*)alloc((size_t)K * SLOTS * 128 * 4);
    float* wbuf      = (float*)alloc((size_t)N * 4 * 4);
    size_t base_need = off;
    unsigned short* abf = (unsigned short*)alloc((size_t)N * 256 * 2);
    unsigned short* Wt  = (unsigned short*)alloc((size_t)K * 64 * 256 * 2);
    size_t mfma_need = off;
    (void)in_sizes; (void)n_in; (void)out_size; (void)base_need;
    bool use_mfma = (ws_size >= mfma_need);

    // bstream (K*E*4 = 25.6 MB) aliases hbf+x (12.8+25.6 MB contiguous):
    // only used in the build phase, before gemm1/gather1 write hbf/x.
    unsigned* bstream = (unsigned*)hbf;

    // ---- batched CSR build: atomic-free 3-pass bucket radix sort ----
    hipMemsetAsync(accum, 0, (size_t)K * SLOTS * 128 * 4, stream);
    hist_pass<<<dim3(PG, K), 256, 0, stream>>>(edge, blockhist, E);
    scan_pass<<<K, 256, 0, stream>>>(blockhist, bbase, rowptr, N, E);
    partition_pass<<<dim3(PG, K), 256, 0, stream>>>(edge, blockhist, bbase, bstream, E);
    bucket_build<<<dim3(NBUCK, K), 256, 0, stream>>>(bbase, bstream, rowptr, dis, adj, N, E);

    if (use_mfma) {
        a2bf_kernel<<<(N * 256 / 4 + 255) / 256, 256, 0, stream>>>(flatten, abf, N * 256 / 4);
        w2bf_kernel<<<K, 256, 0, stream>>>(W1, Wt);
    }

    // gating weights are independent of the expert pipeline
    gate_kernel<<<(int)(((size_t)N * 64 + 255) / 256), 256, 0, stream>>>(
        moe, Wg, bg, wbuf, N);

    // ---- per-expert pipeline ----
    for (int k = 0; k < K; k++) {
        const int* rp = rowptr + (size_t)k * (N + 1);
        const int* aj = adj + (size_t)k * E;
        const float* dk = dis + (size_t)k * N;
        float* ak = accum + (size_t)k * SLOTS * 128;
        if (use_mfma) {
            gemm1_mfma<<<(N + 63) / 64, 256, 0, stream>>>(
                abf, Wt + (size_t)k * 64 * 256, dk, hbf, N);
        } else {
            gemm1_fp32<<<(N + 63) / 64, 256, 0, stream>>>(
                flatten, W1 + (size_t)k * 256 * 64, dk, hbf, N);
        }
        gather1<<<(N + 3) / 4, 256, 0, stream>>>(
            rp, aj, dk, hbf, b1 + (size_t)k * 64, x, ak, N);
        bn_gemm2<<<1024, 256, 0, stream>>>(
            x, ak, gamma + (size_t)k * 64, beta + (size_t)k * 64,
            W2 + (size_t)k * 128, dk, h2all + (size_t)k * N * 2, N);
    }
    // 1568 = 8 XCDs x 196 slots; swizzled (expert, node-block) decode inside
    gather2_all<<<1568, 256, 0, stream>>>(
        rowptr, adj, dis, h2all, b2, agg2, N, E);
    mix_kernel<<<(N + 255) / 256, 256, 0, stream>>>(wbuf, agg2, out, N);
}

// Round 7
// 789.557 us; speedup vs baseline: 1.1425x; 1.0575x over previous
//
#include <hip/hip_runtime.h>
#include <math.h>

#define NN 100000
#define KEXP 4
#define EE 1600000
#define EPSV 1e-5f
#define BSHIFT 9
#define BSIZE 512
#define NBUCK 196       // ceil(100000/512)
#define PCHUNK 4096     // edges per block in hist/partition kernels
#define PG ((EE + PCHUNK - 1) / PCHUNK)   // 391
#define SLOTS 64        // hashed stat accumulator slots
#define STAGECAP 12288  // LDS stage entries for bucket_build (48 KB)

typedef __attribute__((ext_vector_type(8))) short bfrag8;
typedef __attribute__((ext_vector_type(16))) float facc16;

__device__ __forceinline__ unsigned short f2bf(float f) {
    unsigned u = __float_as_uint(f);
    return (unsigned short)((u + 0x7fff + ((u >> 16) & 1)) >> 16);
}
__device__ __forceinline__ float bf_lo(unsigned u) { return __uint_as_float(u << 16); }
__device__ __forceinline__ float bf_hi(unsigned u) { return __uint_as_float(u & 0xffff0000u); }

// ---------------- radix pass 1: per-(block,bucket) histogram, no atomics --
__global__ __launch_bounds__(256) void hist_pass(const int* __restrict__ edge,
                                                 int* __restrict__ blockhist, int E) {
    int k = blockIdx.y, bx = blockIdx.x;
    const int* dp = edge + (size_t)k * 2 * E + E;
    __shared__ int hist[NBUCK];
    for (int i = threadIdx.x; i < NBUCK; i += 256) hist[i] = 0;
    __syncthreads();
    int cb = bx * PCHUNK, ce = cb + PCHUNK;
    if (ce > E) ce = E;
    for (int e = cb + (int)threadIdx.x; e < ce; e += 256)
        atomicAdd(&hist[dp[e] >> BSHIFT], 1);
    __syncthreads();
    for (int i = threadIdx.x; i < NBUCK; i += 256)
        blockhist[((size_t)k * PG + bx) * NBUCK + i] = hist[i];
}

// ---------------- radix pass 2: column scan -> per-block bases + bucket
// bases (blockhist overwritten in place with exclusive per-block prefix) ----
__global__ __launch_bounds__(256) void scan_pass(int* __restrict__ blockhist,
                                                 int* __restrict__ bbase,
                                                 int* __restrict__ rowptr,
                                                 int n, int E) {
    int k = blockIdx.x;
    int t = threadIdx.x;
    int running = 0;
    if (t < NBUCK) {
        for (int j = 0; j < PG; j++) {
            size_t idx = ((size_t)k * PG + j) * NBUCK + t;
            int v = blockhist[idx];
            blockhist[idx] = running;
            running += v;
        }
    }
    __shared__ int sd[256];
    sd[t] = (t < NBUCK) ? running : 0;
    __syncthreads();
    for (int o = 1; o < 256; o <<= 1) {
        int x = (t >= o) ? sd[t - o] : 0;
        __syncthreads();
        sd[t] += x;
        __syncthreads();
    }
    if (t < NBUCK) bbase[k * (NBUCK + 1) + t] = sd[t] - running;
    if (t == 0) {
        bbase[k * (NBUCK + 1) + NBUCK] = E;
        rowptr[(size_t)k * (n + 1) + n] = E;
    }
}

// ---------------- radix pass 3: LDS-staged local sort + coalesced dump ----
__global__ __launch_bounds__(256) void partition_pass(const int* __restrict__ edge,
                                                      const int* __restrict__ blockhist,
                                                      const int* __restrict__ bbase,
                                                      unsigned* __restrict__ bstream,
                                                      int E) {
    int k = blockIdx.y, bx = blockIdx.x;
    int t = threadIdx.x;
    __shared__ int hist[NBUCK];        // counts -> cursors
    __shared__ int lofs[NBUCK + 1];    // local exclusive prefix
    __shared__ int gbase[NBUCK];       // global dest base for this block
    __shared__ int tmp[256];
    __shared__ unsigned stage[PCHUNK]; // 16 KB
    for (int i = t; i < NBUCK; i += 256) {
        hist[i] = 0;
        gbase[i] = bbase[k * (NBUCK + 1) + i] + blockhist[((size_t)k * PG + bx) * NBUCK + i];
    }
    __syncthreads();
    const int* sp = edge + (size_t)k * 2 * E;
    const int* dp = sp + E;
    int cb = bx * PCHUNK, ce = cb + PCHUNK;
    if (ce > E) ce = E;
    int cnt = ce - cb;
    for (int e = cb + t; e < ce; e += 256)
        atomicAdd(&hist[dp[e] >> BSHIFT], 1);
    __syncthreads();
    int v = (t < NBUCK) ? hist[t] : 0;
    tmp[t] = v;
    __syncthreads();
    for (int o = 1; o < 256; o <<= 1) {
        int x = (t >= o) ? tmp[t - o] : 0;
        __syncthreads();
        tmp[t] += x;
        __syncthreads();
    }
    if (t < NBUCK) { lofs[t] = tmp[t] - v; hist[t] = tmp[t] - v; }
    if (t == 0) lofs[NBUCK] = cnt;
    __syncthreads();
    for (int e = cb + t; e < ce; e += 256) {
        int s = sp[e];
        int d = dp[e];
        int r = atomicAdd(&hist[d >> BSHIFT], 1);
        stage[r] = ((unsigned)(d & (BSIZE - 1)) << 17) | (unsigned)s;
    }
    __syncthreads();
    unsigned* bs = bstream + (size_t)k * E;
    for (int i = t; i < cnt; i += 256) {
        int lo = 0, hi = NBUCK;
        while (hi - lo > 1) {
            int mid = (lo + hi) >> 1;
            if (lofs[mid] <= i) lo = mid; else hi = mid;
        }
        bs[gbase[lo] + (i - lofs[lo])] = stage[i];
    }
}

// ---------------- per-bucket: degree hist + scan + rowptr + dis + LDS-staged
// node sort + dense coalesced dump (write amp ~1x). ----------------------
__global__ __launch_bounds__(256) void bucket_build(const int* __restrict__ bbase,
                                                    const unsigned* __restrict__ bstream,
                                                    int* __restrict__ rowptr,
                                                    float* __restrict__ dis,
                                                    int* __restrict__ adj,
                                                    int n, int E) {
    int k = blockIdx.y;
    int b = blockIdx.x;
    int nb = b << BSHIFT;
    int t = threadIdx.x;
    __shared__ int hist[BSIZE];
    __shared__ int curx[BSIZE];      // LOCAL cursors (offset within bucket)
    __shared__ int tmp[256];
    __shared__ int stage[STAGECAP];  // 48 KB
    hist[t] = 0;
    hist[t + 256] = 0;
    __syncthreads();
    int beg = bbase[k * (NBUCK + 1) + b];
    int end = bbase[k * (NBUCK + 1) + b + 1];
    int cnt = end - beg;
    const unsigned* bs = bstream + (size_t)k * E;
    for (int p = beg + t; p < end; p += 256) {
        atomicAdd(&hist[bs[p] >> 17], 1);
    }
    __syncthreads();
    int a0 = hist[2 * t], a1 = hist[2 * t + 1];
    tmp[t] = a0 + a1;
    __syncthreads();
    for (int o = 1; o < 256; o <<= 1) {
        int x = (t >= o) ? tmp[t - o] : 0;
        __syncthreads();
        tmp[t] += x;
        __syncthreads();
    }
    int ex = tmp[t] - (a0 + a1);  // exclusive prefix over pairs (local)
    int l0 = ex;
    int l1 = ex + a0;
    curx[2 * t] = l0;
    curx[2 * t + 1] = l1;
    int* rp = rowptr + (size_t)k * (n + 1);
    float* dk = dis + (size_t)k * n;
    int node0 = nb + 2 * t, node1 = nb + 2 * t + 1;
    if (node0 < n) { rp[node0] = beg + l0; dk[node0] = rsqrtf((float)a0 + 2.0f); }
    if (node1 < n) { rp[node1] = beg + l1; dk[node1] = rsqrtf((float)a1 + 2.0f); }
    __syncthreads();
    int* aj = adj + (size_t)k * E;
    for (int p = beg + t; p < end; p += 256) {
        unsigned pk = bs[p];
        int pos = atomicAdd(&curx[pk >> 17], 1);
        int sv = (int)(pk & 0x1FFFFu);
        if (pos < STAGECAP) stage[pos] = sv;      // expected path
        else aj[beg + pos] = sv;                  // pathological overflow
    }
    __syncthreads();
    // dense dump: scalar head to 16B alignment, uint4 body, scalar tail
    int lim = cnt < STAGECAP ? cnt : STAGECAP;
    int head = (4 - (beg & 3)) & 3;
    if (head > lim) head = lim;
    if (t < head) aj[beg + t] = stage[t];
    int nv = (lim - head) >> 2;                   // full uint4 groups
    for (int i = t; i < nv; i += 256) {
        int s4 = head + 4 * i;
        uint4 v = make_uint4((unsigned)stage[s4], (unsigned)stage[s4 + 1],
                             (unsigned)stage[s4 + 2], (unsigned)stage[s4 + 3]);
        *(uint4*)&aj[beg + s4] = v;
    }
    int tail0 = head + 4 * nv;
    for (int i = tail0 + t; i < lim; i += 256) aj[beg + i] = stage[i];
}

// ---------------- convert flatten -> bf16 (once) ----------------
__global__ __launch_bounds__(256) void a2bf_kernel(const float* __restrict__ A,
                                                   unsigned short* __restrict__ abf,
                                                   int n4) {
    int i = blockIdx.x * 256 + threadIdx.x;
    if (i >= n4) return;
    float4 v = ((const float4*)A)[i];
    ushort4 o;
    o.x = f2bf(v.x); o.y = f2bf(v.y); o.z = f2bf(v.z); o.w = f2bf(v.w);
    ((ushort4*)abf)[i] = o;
}

// ---------------- convert + transpose W1 -> Wt[k][col][kk] bf16 ----------
__global__ __launch_bounds__(256) void w2bf_kernel(const float* __restrict__ W1,
                                                   unsigned short* __restrict__ Wt) {
    int k = blockIdx.x;
    for (int idx = threadIdx.x; idx < 64 * 256; idx += 256) {
        int c = idx >> 8;       // col 0..63
        int kk = idx & 255;     // k 0..255
        Wt[(size_t)k * 64 * 256 + c * 256 + kk] = f2bf(W1[(size_t)k * 256 * 64 + kk * 64 + c]);
    }
}

// ---------------- GEMM1 (MFMA): ph1[k] = dis[k] * (A @ W[k]); expert from
// blockIdx.y (merged launch: gridDim.y=K; per-expert: gridDim.y=1 with
// pre-offset pointers). ---------------------------------------------------
__global__ __launch_bounds__(256) void gemm1_mfma_all(
    const unsigned short* __restrict__ abf,   // [M,256] bf16
    const unsigned short* __restrict__ Wtall, // [gridDim.y][64,256] bf16
    const float* __restrict__ dis,            // [gridDim.y][M]
    unsigned short* __restrict__ phall,       // [gridDim.y][M,64] bf16
    int M) {
    int k = blockIdx.y;
    const unsigned short* Wt = Wtall + (size_t)k * 64 * 256;
    const float* dk = dis + (size_t)k * M;
    unsigned short* phbf = phall + (size_t)k * M * 64;
    __shared__ __align__(16) unsigned short As[64][72];  // [row][k], +8 pad
    __shared__ __align__(16) unsigned short Bs[64][72];  // [col][k]
    int t = threadIdx.x;
    int row0 = blockIdx.x * 64;
    int wid = t >> 6, lane = t & 63;
    int qr = wid >> 1, qc = wid & 1;
    facc16 acc;
    for (int i = 0; i < 16; i++) acc[i] = 0.f;

    for (int kc = 0; kc < 256; kc += 64) {
        for (int i = 0; i < 2; i++) {
            int fid = t + i * 256;    // 0..511
            int r = fid >> 3;
            int o = (fid & 7) * 8;
            int row = row0 + r;
            uint4 v = make_uint4(0u, 0u, 0u, 0u);
            if (row < M) v = *(const uint4*)&abf[(size_t)row * 256 + kc + o];
            *(uint4*)&As[r][o] = v;
        }
        for (int i = 0; i < 2; i++) {
            int fid = t + i * 256;
            int c = fid >> 3;
            int o = (fid & 7) * 8;
            uint4 v = *(const uint4*)&Wt[(size_t)c * 256 + kc + o];
            *(uint4*)&Bs[c][o] = v;
        }
        __syncthreads();
        int arow = qr * 32 + (lane & 31);
        int bcol = qc * 32 + (lane & 31);
        int ko = (lane >> 5) * 8;
        for (int kk = 0; kk < 64; kk += 16) {
            bfrag8 a = *(const bfrag8*)&As[arow][kk + ko];
            bfrag8 b = *(const bfrag8*)&Bs[bcol][kk + ko];
            acc = __builtin_amdgcn_mfma_f32_32x32x16_bf16(a, b, acc, 0, 0, 0);
        }
        __syncthreads();
    }
    int col = qc * 32 + (lane & 31);
    for (int i = 0; i < 16; i++) {
        int rl = (i & 3) + 8 * (i >> 2) + 4 * (lane >> 5);
        int row = row0 + qr * 32 + rl;
        if (row < M) phbf[(size_t)row * 64 + col] = f2bf(dk[row] * acc[i]);
    }
}

// ---------------- GEMM1 fallback (fp32 VALU), expert from blockIdx.y ------
__global__ __launch_bounds__(256) void gemm1_fp32_all(
    const float* __restrict__ A, const float* __restrict__ W1,
    const float* __restrict__ dis,
    unsigned short* __restrict__ phall, int M) {
    int k = blockIdx.y;
    const float* W = W1 + (size_t)k * 256 * 64;
    const float* dk = dis + (size_t)k * M;
    unsigned short* phbf = phall + (size_t)k * M * 64;
    __shared__ __align__(16) float As[64][65];
    __shared__ __align__(16) float Ws[64][68];
    int t = threadIdx.x;
    int row0 = blockIdx.x * 64;
    int tr = t >> 4;
    int tc = t & 15;
    float acc[4][4] = {{0.f}};
    for (int kc = 0; kc < 256; kc += 64) {
        for (int i = 0; i < 4; i++) {
            int fid = t + i * 256;
            int r = fid >> 4;
            int c4 = (fid & 15) << 2;
            int row = row0 + r;
            float4 v = make_float4(0.f, 0.f, 0.f, 0.f);
            if (row < M) v = *(const float4*)&A[(size_t)row * 256 + kc + c4];
            As[r][c4] = v.x; As[r][c4 + 1] = v.y; As[r][c4 + 2] = v.z; As[r][c4 + 3] = v.w;
        }
        for (int i = 0; i < 4; i++) {
            int fid = t + i * 256;
            int r = fid >> 4;
            int c4 = (fid & 15) << 2;
            float4 v = *(const float4*)&W[(size_t)(kc + r) * 64 + c4];
            *(float4*)&Ws[r][c4] = v;
        }
        __syncthreads();
        for (int kk = 0; kk < 64; kk++) {
            float a0 = As[tr * 4 + 0][kk];
            float a1 = As[tr * 4 + 1][kk];
            float a2 = As[tr * 4 + 2][kk];
            float a3 = As[tr * 4 + 3][kk];
            float4 w = *(const float4*)&Ws[kk][tc * 4];
            acc[0][0] += a0 * w.x; acc[0][1] += a0 * w.y; acc[0][2] += a0 * w.z; acc[0][3] += a0 * w.w;
            acc[1][0] += a1 * w.x; acc[1][1] += a1 * w.y; acc[1][2] += a1 * w.z; acc[1][3] += a1 * w.w;
            acc[2][0] += a2 * w.x; acc[2][1] += a2 * w.y; acc[2][2] += a2 * w.z; acc[2][3] += a2 * w.w;
            acc[3][0] += a3 * w.x; acc[3][1] += a3 * w.y; acc[3][2] += a3 * w.z; acc[3][3] += a3 * w.w;
        }
        __syncthreads();
    }
    for (int i = 0; i < 4; i++) {
        int row = row0 + tr * 4 + i;
        if (row >= M) continue;
        float dn = dk[row];
        ushort4 o;
        o.x = f2bf(dn * acc[i][0]); o.y = f2bf(dn * acc[i][1]);
        o.z = f2bf(dn * acc[i][2]); o.w = f2bf(dn * acc[i][3]);
        *(ushort4*)&phbf[(size_t)row * 64 + 4 * tc] = o;
    }
}

// ---------------- gather agg1.  merged=1: all experts in one launch with
// XCD-pinned decode (expert k -> XCD pair {2k,2k+1} under round-robin,
// each pair's 8MB L2 backs one 12.8MB ph table).  merged=0: single expert,
// pre-offset pointers, nb4 = blockIdx.x.  Wave/node, 8 rows in flight. ----
__global__ __launch_bounds__(256) void gather1_all(const int* __restrict__ rowptr,
                                                   const int* __restrict__ adj,
                                                   const float* __restrict__ dis,
                                                   const unsigned short* __restrict__ phall,
                                                   const float* __restrict__ b1all,
                                                   float* __restrict__ xall,
                                                   float* __restrict__ accum,
                                                   int n, int E, int merged) {
    int B = blockIdx.x;
    int k, nb4;
    if (merged) {
        k = (B >> 1) & 3;                       // expert from XCD pair
        nb4 = (((B >> 3) << 1) | (B & 1));      // node-block 0..24999
    } else {
        k = 0;
        nb4 = B;
    }
    const int* rp = rowptr + (size_t)k * (n + 1);
    const int* aj = adj + (size_t)k * E;
    const unsigned short* phbf = phall + (size_t)k * n * 64;
    const float* b1 = b1all + (size_t)k * 64;
    float* x = xall + (size_t)k * n * 64;

    __shared__ float ls[4][64];
    __shared__ float lq[4][64];
    ((float*)ls)[threadIdx.x] = 0.f;
    ((float*)lq)[threadIdx.x] = 0.f;
    __syncthreads();
    int w = threadIdx.x >> 6;
    int node = nb4 * 4 + w;
    int lane = threadIdx.x & 63;
    int g = lane >> 4;       // edge group 0..3
    int q = lane & 15;       // channel quad: channels 4q..4q+3
    if (node < n) {
        int beg = rp[node], end = rp[node + 1];
        float a0 = 0.f, a1 = 0.f, a2 = 0.f, a3 = 0.f;
        float c0 = 0.f, c1 = 0.f, c2 = 0.f, c3 = 0.f;
        int j = beg;
        for (; j + 8 <= end; j += 8) {
            int s0 = aj[j + g];
            int s1 = aj[j + 4 + g];
            uint2 u0 = *(const uint2*)&phbf[(size_t)s0 * 64 + 4 * q];
            uint2 u1 = *(const uint2*)&phbf[(size_t)s1 * 64 + 4 * q];
            a0 += bf_lo(u0.x); a1 += bf_hi(u0.x);
            a2 += bf_lo(u0.y); a3 += bf_hi(u0.y);
            c0 += bf_lo(u1.x); c1 += bf_hi(u1.x);
            c2 += bf_lo(u1.y); c3 += bf_hi(u1.y);
        }
        for (; j < end; j += 4) {
            int jj = j + g;
            if (jj < end) {
                int s = aj[jj];
                uint2 u = *(const uint2*)&phbf[(size_t)s * 64 + 4 * q];
                a0 += bf_lo(u.x); a1 += bf_hi(u.x);
                a2 += bf_lo(u.y); a3 += bf_hi(u.y);
            }
        }
        a0 += c0; a1 += c1; a2 += c2; a3 += c3;
        // reduce the 4 edge-groups (lanes q, 16+q, 32+q, 48+q)
        a0 += __shfl_xor(a0, 16); a1 += __shfl_xor(a1, 16);
        a2 += __shfl_xor(a2, 16); a3 += __shfl_xor(a3, 16);
        a0 += __shfl_xor(a0, 32); a1 += __shfl_xor(a1, 32);
        a2 += __shfl_xor(a2, 32); a3 += __shfl_xor(a3, 32);
        if (g == 0) {
            float dn = dis[(size_t)k * n + node];
            uint2 us = *(const uint2*)&phbf[(size_t)node * 64 + 4 * q];
            float4 bv = *(const float4*)&b1[4 * q];
            float v0 = dn * (a0 + 2.f * bf_lo(us.x)) + bv.x;
            float v1 = dn * (a1 + 2.f * bf_hi(us.x)) + bv.y;
            float v2 = dn * (a2 + 2.f * bf_lo(us.y)) + bv.z;
            float v3 = dn * (a3 + 2.f * bf_hi(us.y)) + bv.w;
            v0 = fmaxf(v0, 0.f); v1 = fmaxf(v1, 0.f);
            v2 = fmaxf(v2, 0.f); v3 = fmaxf(v3, 0.f);
            *(float4*)&x[(size_t)node * 64 + 4 * q] = make_float4(v0, v1, v2, v3);
            *(float4*)&ls[w][4 * q] = make_float4(v0, v1, v2, v3);
            *(float4*)&lq[w][4 * q] = make_float4(v0 * v0, v1 * v1, v2 * v2, v3 * v3);
        }
    }
    __syncthreads();
    if (threadIdx.x < 64) {
        int c = threadIdx.x;
        float S = ls[0][c] + ls[1][c] + ls[2][c] + ls[3][c];
        float Q = lq[0][c] + lq[1][c] + lq[2][c] + lq[3][c];
        float* slot = accum + (size_t)k * SLOTS * 128 + (size_t)(nb4 & (SLOTS - 1)) * 128;
        unsafeAtomicAdd(&slot[c], S);
        unsafeAtomicAdd(&slot[64 + c], Q);
    }
}

// ---------------- BN apply + GEMM2 (64 -> 2), expert from blockIdx.y ------
__global__ __launch_bounds__(256) void bn_gemm2_all(const float* __restrict__ xall,
                                                    const float* __restrict__ accum,
                                                    const float* __restrict__ gall,
                                                    const float* __restrict__ btall,
                                                    const float* __restrict__ W2all,
                                                    const float* __restrict__ dis,
                                                    float* __restrict__ h2all, int M) {
    int k = blockIdx.y;
    const float* x = xall + (size_t)k * M * 64;
    const float* acb = accum + (size_t)k * SLOTS * 128;
    const float* g = gall + (size_t)k * 64;
    const float* bt = btall + (size_t)k * 64;
    const float* W2 = W2all + (size_t)k * 128;
    const float* dk = dis + (size_t)k * M;
    float* ph = h2all + (size_t)k * M * 2;
    __shared__ float a_s[64], b_s[64];
    int t = threadIdx.x;
    if (t < 64) {
        float S = 0.f, Q = 0.f;
        for (int s = 0; s < SLOTS; s++) {
            S += acb[(size_t)s * 128 + t];
            Q += acb[(size_t)s * 128 + 64 + t];
        }
        float mu = S / (float)M;
        float var = Q / (float)M - mu * mu;
        float istdg = rsqrtf(var + EPSV) * g[t];
        a_s[t] = istdg;
        b_s[t] = bt[t] - mu * istdg;
    }
    __syncthreads();
    int w = t >> 6;
    int c = t & 63;
    float a = a_s[c], b = b_s[c];
    float w20 = W2[c * 2], w21 = W2[c * 2 + 1];
    for (int node = blockIdx.x * 4 + w; node < M; node += gridDim.x * 4) {
        float v = x[(size_t)node * 64 + c] * a + b;
        float p0 = v * w20;
        float p1 = v * w21;
        for (int off = 32; off; off >>= 1) {
            p0 += __shfl_down(p0, off);
            p1 += __shfl_down(p1, off);
        }
        if (c == 0) {
            float dn = dk[node];
            *(float2*)&ph[(size_t)node * 2] = make_float2(dn * p0, dn * p1);
        }
    }
}

// ---------------- gather agg2: thread per node, all experts, XCD-pinned --
__global__ __launch_bounds__(256) void gather2_all(const int* __restrict__ rowptr,
                                                   const int* __restrict__ adj,
                                                   const float* __restrict__ dis,
                                                   const float* __restrict__ phall,
                                                   const float* __restrict__ b2,
                                                   float* __restrict__ agg2,
                                                   int n, int E) {
    int B = blockIdx.x;
    int k = (B & 7) >> 1;                      // expert 0..3 from XCD pair
    int jb = ((B >> 3) << 1) | (B & 1);        // node-block 0..391
    int node = jb * 256 + (int)threadIdx.x;
    if (node >= n) return;
    const int* rp = rowptr + (size_t)k * (n + 1);
    const int* aj = adj + (size_t)k * E;
    const float* ph = phall + (size_t)k * n * 2;
    float dn = dis[(size_t)k * n + node];
    int beg = rp[node], end = rp[node + 1];
    float a0 = 0.f, a1 = 0.f;
    int j = beg;
    for (; j + 2 <= end; j += 2) {
        int s0 = aj[j], s1 = aj[j + 1];
        float2 v0 = *(const float2*)&ph[(size_t)s0 * 2];
        float2 v1 = *(const float2*)&ph[(size_t)s1 * 2];
        a0 += v0.x + v1.x;
        a1 += v0.y + v1.y;
    }
    if (j < end) {
        int s0 = aj[j];
        float2 v0 = *(const float2*)&ph[(size_t)s0 * 2];
        a0 += v0.x;
        a1 += v0.y;
    }
    float2 pn = *(const float2*)&ph[(size_t)node * 2];
    float2 o;
    o.x = dn * (a0 + 2.f * pn.x) + b2[k * 2];
    o.y = dn * (a1 + 2.f * pn.y) + b2[k * 2 + 1];
    *(float2*)&agg2[((size_t)k * n + node) * 2] = o;
}

// ---------------- gating: THREAD per node (Wg staged in LDS, no shuffles) --
__global__ __launch_bounds__(256) void gate_kernel(const float* __restrict__ moe,
                                                   const float* __restrict__ Wg,
                                                   const float* __restrict__ bg,
                                                   float* __restrict__ wbuf, int M) {
    __shared__ float wg_s[1024];
    for (int i = threadIdx.x; i < 1024; i += 256) wg_s[i] = Wg[i];
    __syncthreads();
    int n = blockIdx.x * 256 + threadIdx.x;
    if (n >= M) return;
    const float4* row = (const float4*)&moe[(size_t)n * 256];
    float a0 = 0.f, a1 = 0.f, a2 = 0.f, a3 = 0.f;
    #pragma unroll 8
    for (int j = 0; j < 64; j++) {
        float4 v = row[j];
        const float* wj = &wg_s[j * 16];
        a0 += v.x * wj[0] + v.y * wj[4] + v.z * wj[8]  + v.w * wj[12];
        a1 += v.x * wj[1] + v.y * wj[5] + v.z * wj[9]  + v.w * wj[13];
        a2 += v.x * wj[2] + v.y * wj[6] + v.z * wj[10] + v.w * wj[14];
        a3 += v.x * wj[3] + v.y * wj[7] + v.z * wj[11] + v.w * wj[15];
    }
    float g0 = a0 + bg[0], g1 = a1 + bg[1], g2 = a2 + bg[2], g3 = a3 + bg[3];
    float m = fmaxf(fmaxf(g0, g1), fmaxf(g2, g3));
    float w0 = expf(g0 - m), w1 = expf(g1 - m), w2 = expf(g2 - m), w3 = expf(g3 - m);
    float inv = 1.f / (w0 + w1 + w2 + w3);
    *(float4*)&wbuf[(size_t)n * 4] = make_float4(w0 * inv, w1 * inv, w2 * inv, w3 * inv);
}

// ---------------- mixture epilogue: thread per node ----------------------
__global__ __launch_bounds__(256) void mix_kernel(const float* __restrict__ wbuf,
                                                  const float* __restrict__ agg2,  // [K][N][2]
                                                  float* __restrict__ out, int M) {
    int n = blockIdx.x * 256 + threadIdx.x;
    if (n >= M) return;
    float4 wv = *(const float4*)&wbuf[(size_t)n * 4];
    float wk[4] = {wv.x, wv.y, wv.z, wv.w};
    float o0 = 0.f, o1 = 0.f, q0 = 0.f, q1 = 0.f;
    for (int kk = 0; kk < 4; kk++) {
        float2 l = *(const float2*)&agg2[((size_t)kk * M + n) * 2];
        float mm = fmaxf(l.x, l.y);
        float lse = mm + logf(expf(l.x - mm) + expf(l.y - mm));
        float lp0 = l.x - lse, lp1 = l.y - lse;
        o0 += wk[kk] * lp0; o1 += wk[kk] * lp1;
        q0 += wk[kk] * expf(lp0); q1 += wk[kk] * expf(lp1);
    }
    *(float2*)&out[(size_t)n * 2] = make_float2(o0, o1);
    *(float2*)&out[(size_t)2 * M + n * 2] = make_float2(q0, q1);
}

extern "C" void kernel_launch(void* const* d_in, const int* in_sizes, int n_in,
                              void* d_out, int out_size, void* d_ws, size_t ws_size,
                              hipStream_t stream) {
    const float* flatten = (const float*)d_in[0];
    const float* moe     = (const float*)d_in[1];
    const int*   edge    = (const int*)d_in[2];   // [K][2][E]
    const float* W1      = (const float*)d_in[3]; // [K][256][64]
    const float* b1      = (const float*)d_in[4]; // [K][64]
    const float* gamma   = (const float*)d_in[5];
    const float* beta    = (const float*)d_in[6];
    const float* W2      = (const float*)d_in[7]; // [K][64][2]
    const float* b2      = (const float*)d_in[8]; // [K][2]
    const float* Wg      = (const float*)d_in[9]; // [256][4]
    const float* bg      = (const float*)d_in[10];
    float* out = (float*)d_out;

    const int N = NN, E = EE, K = KEXP;

    char* ws = (char*)d_ws;
    size_t off = 0;
    auto alloc = [&](size_t bytes) -> void* {
        void* p = (void*)(ws + off);
        off += (bytes + 255) & ~(size_t)255;
        return p;
    };
    // ---- common buffers (both layouts) ----
    int*   rowptr    = (int*)alloc((size_t)K * (N + 1) * 4);
    float* dis       = (float*)alloc((size_t)K * N * 4);
    int*   blockhist = (int*)alloc((size_t)K * PG * NBUCK * 4);
    int*   bbase     = (int*)alloc((size_t)K * (NBUCK + 1) * 4);
    int*   adj       = (int*)alloc((size_t)K * E * 4);
    float* h2all     = (float*)alloc((size_t)K * N * 2 * 4);
    float* agg2      = (float*)alloc((size_t)K * N * 2 * 4);
    float* accum     = (float*)alloc((size_t)K * SLOTS * 128 * 4);
    float* wbuf      = (float*)alloc((size_t)N * 4 * 4);
    unsigned short* Wt = (unsigned short*)alloc((size_t)K * 64 * 256 * 2);
    size_t common_end = off;

    // ---- layout A (merged, ~191MB): phall[K] + xall[K]; abf aliases xall
    // (abf is dead before gather1_all writes xall); bstream aliases phall.
    unsigned short* phallA = (unsigned short*)alloc((size_t)K * N * 64 * 2); // 51.2MB
    float* xallA = (float*)alloc((size_t)K * N * 64 * 4);                    // 102.4MB
    size_t merged_need = off;

    // ---- layout B (per-expert fallback, footprint of the proven r4 build)
    off = common_end;
    unsigned short* hbfB = (unsigned short*)alloc((size_t)N * 64 * 2);   // 12.8MB
    float* xB = (float*)alloc((size_t)N * 64 * 4);                       // 25.6MB
    size_t fb_base_need = off;
    unsigned short* abfB = (unsigned short*)alloc((size_t)N * 256 * 2);  // 51.2MB
    size_t fb_mfma_need = off;
    (void)in_sizes; (void)n_in; (void)out_size; (void)fb_base_need;

    bool merged = (ws_size >= merged_need);
    bool fb_mfma = (ws_size >= fb_mfma_need);

    unsigned* bstream = merged ? (unsigned*)phallA : (unsigned*)hbfB;
    // (fallback: hbfB+xB are contiguous 38.4MB >= 25.6MB bstream need)

    // ---- batched CSR build: atomic-free 3-pass bucket radix sort ----
    hipMemsetAsync(accum, 0, (size_t)K * SLOTS * 128 * 4, stream);
    hist_pass<<<dim3(PG, K), 256, 0, stream>>>(edge, blockhist, E);
    scan_pass<<<K, 256, 0, stream>>>(blockhist, bbase, rowptr, N, E);
    partition_pass<<<dim3(PG, K), 256, 0, stream>>>(edge, blockhist, bbase, bstream, E);
    bucket_build<<<dim3(NBUCK, K), 256, 0, stream>>>(bbase, bstream, rowptr, dis, adj, N, E);

    // gating weights are independent of the expert pipeline
    gate_kernel<<<(N + 255) / 256, 256, 0, stream>>>(moe, Wg, bg, wbuf, N);

    if (merged) {
        unsigned short* abf = (unsigned short*)xallA;  // alias: dead before x写
        a2bf_kernel<<<(N * 256 / 4 + 255) / 256, 256, 0, stream>>>(flatten, abf, N * 256 / 4);
        w2bf_kernel<<<K, 256, 0, stream>>>(W1, Wt);
        gemm1_mfma_all<<<dim3((N + 63) / 64, K), 256, 0, stream>>>(
            abf, Wt, dis, phallA, N);
        gather1_all<<<N, 256, 0, stream>>>(
            rowptr, adj, dis, phallA, b1, xallA, accum, N, E, 1);
        bn_gemm2_all<<<dim3(1024, K), 256, 0, stream>>>(
            xallA, accum, gamma, beta, W2, dis, h2all, N);
    } else {
        if (fb_mfma) {
            a2bf_kernel<<<(N * 256 / 4 + 255) / 256, 256, 0, stream>>>(flatten, abfB, N * 256 / 4);
            w2bf_kernel<<<K, 256, 0, stream>>>(W1, Wt);
        }
        for (int k = 0; k < K; k++) {
            if (fb_mfma) {
                gemm1_mfma_all<<<dim3((N + 63) / 64, 1), 256, 0, stream>>>(
                    abfB, Wt + (size_t)k * 64 * 256, dis + (size_t)k * N, hbfB, N);
            } else {
                gemm1_fp32_all<<<dim3((N + 63) / 64, 1), 256, 0, stream>>>(
                    flatten, W1 + (size_t)k * 256 * 64, dis + (size_t)k * N, hbfB, N);
            }
            gather1_all<<<(N + 3) / 4, 256, 0, stream>>>(
                rowptr + (size_t)k * (N + 1), adj + (size_t)k * E,
                dis + (size_t)k * N, hbfB, b1 + (size_t)k * 64, xB,
                accum + (size_t)k * SLOTS * 128, N, E, 0);
            bn_gemm2_all<<<dim3(1024, 1), 256, 0, stream>>>(
                xB, accum + (size_t)k * SLOTS * 128, gamma + (size_t)k * 64,
                beta + (size_t)k * 64, W2 + (size_t)k * 128,
                dis + (size_t)k * N, h2all + (size_t)k * N * 2, N);
        }
    }
    // 1568 = 8 XCDs x 196 slots; swizzled (expert, node-block) decode inside
    gather2_all<<<1568, 256, 0, stream>>>(
        rowptr, adj, dis, h2all, b2, agg2, N, E);
    mix_kernel<<<(N + 255) / 256, 256, 0, stream>>>(wbuf, agg2, out, N);
}